// Round 1
// 435.302 us; speedup vs baseline: 1.0796x; 1.0796x over previous
//
#include <hip/hip_runtime.h>

#define BB 64
#define TO 36
#define TW 32
#define DD 512

typedef short short8 __attribute__((ext_vector_type(8)));
typedef float floatx4 __attribute__((ext_vector_type(4)));

// ---- helpers -------------------------------------------------------------

__device__ __forceinline__ unsigned short f2bf(float f) {
  // round-to-nearest-even fp32 -> bf16 (inputs are sane, no NaN handling)
  unsigned int x = __builtin_bit_cast(unsigned int, f);
  x += 0x7FFFu + ((x >> 16) & 1u);
  return (unsigned short)(x >> 16);
}

__device__ __forceinline__ short8 ld8(const unsigned short* p) {
  return __builtin_bit_cast(short8, *(const uint4*)p);
}

// ---- prep: f32->bf16 conversions + o transpose ---------------------------
// blocks 0..511    : w  (64*32*512 = 1,048,576 floats, 8/thread)
// blocks 512..1087 : u  (64*36*512 = 1,179,648 floats, 8/thread)
// blocks 1088..1215: ot[b][d][64] bf16, o-index padded 36->64 with zeros
__global__ __launch_bounds__(256) void prep_kernel(
    const float* __restrict__ o_g, const float* __restrict__ u_g,
    const float* __restrict__ w_g, unsigned short* __restrict__ wbf,
    unsigned short* __restrict__ ubf, unsigned short* __restrict__ ot) {
  const int blk = blockIdx.x, tid = threadIdx.x;
  if (blk < 512) {
    int i8 = blk * 256 + tid;
    const float4* src = (const float4*)w_g;
    float4 f0 = src[i8 * 2], f1 = src[i8 * 2 + 1];
    uint4 d;
    d.x = (unsigned)f2bf(f0.x) | ((unsigned)f2bf(f0.y) << 16);
    d.y = (unsigned)f2bf(f0.z) | ((unsigned)f2bf(f0.w) << 16);
    d.z = (unsigned)f2bf(f1.x) | ((unsigned)f2bf(f1.y) << 16);
    d.w = (unsigned)f2bf(f1.z) | ((unsigned)f2bf(f1.w) << 16);
    ((uint4*)wbf)[i8] = d;
  } else if (blk < 1088) {
    int i8 = (blk - 512) * 256 + tid;
    const float4* src = (const float4*)u_g;
    float4 f0 = src[i8 * 2], f1 = src[i8 * 2 + 1];
    uint4 d;
    d.x = (unsigned)f2bf(f0.x) | ((unsigned)f2bf(f0.y) << 16);
    d.y = (unsigned)f2bf(f0.z) | ((unsigned)f2bf(f0.w) << 16);
    d.z = (unsigned)f2bf(f1.x) | ((unsigned)f2bf(f1.y) << 16);
    d.w = (unsigned)f2bf(f1.z) | ((unsigned)f2bf(f1.w) << 16);
    ((uint4*)ubf)[i8] = d;
  } else {
    int t2 = (blk - 1088) * 256 + tid;  // 32768 threads: (b, d)
    int b = t2 >> 9, d = t2 & 511;
    uint4 bufv[8];
    unsigned short* buf = (unsigned short*)bufv;
#pragma unroll
    for (int o = 0; o < 64; ++o)
      buf[o] = (o < TO) ? f2bf(o_g[((b * TO + o) << 9) + d]) : (unsigned short)0;
    uint4* dst = (uint4*)(ot + ((size_t)((b << 9) + d) << 6));
#pragma unroll
    for (int i = 0; i < 8; ++i) dst[i] = bufv[i];
  }
}

// ---- main: fused scores->softmax->att_V_o->logits ------------------------
// 4 waves per block share one b (L1 reuse of ubf/ot); wave wv handles
// wb = blockIdx.y*4 + wv.  GEMM2 uses swapped MFMA operands so each lane
// holds 4 consecutive d -> float4 w loads and realigned float4 attV stores.
__global__ __launch_bounds__(256) void main_kernel(
    const float* __restrict__ w_g,
    const unsigned short* __restrict__ wbf,
    const unsigned short* __restrict__ ubf,
    const unsigned short* __restrict__ ot,
    float* __restrict__ logits_ws,
    float* __restrict__ att_out,
    float* __restrict__ attV_out) {
  const int b = blockIdx.x;
  const int wv = threadIdx.x >> 6;          // wave 0..3
  const int wb = blockIdx.y * 4 + wv;
  const int lane = threadIdx.x & 63;
  const int c = lane & 15;   // col within 16x16 tile
  const int q = lane >> 4;   // quad 0..3

  __shared__ unsigned short att_s[4][TW][72];  // per-wave bf16 att, K-pad to 64
  {
    unsigned int* p = (unsigned int*)&att_s[wv][0][0];  // 32*72/2 = 1152 dwords
#pragma unroll
    for (int i = 0; i < 18; ++i) p[lane + 64 * i] = 0u;
  }

  // ---------------- GEMM1: scores[t][o] = w[t,:].u[o,:] ------------------
  const unsigned short* wbp = wbf + (size_t)wb * TW * DD;
  const unsigned short* ubp = ubf + (size_t)b * TO * DD;

  floatx4 acc[2][3];
#pragma unroll
  for (int i = 0; i < 2; ++i)
#pragma unroll
    for (int j = 0; j < 3; ++j) acc[i][j] = (floatx4){0.f, 0.f, 0.f, 0.f};

  int r2 = 32 + c; if (r2 > 35) r2 = 35;  // clamp: cols 36..47 discarded later
#pragma unroll 2
  for (int kk = 0; kk < 16; ++kk) {
    int k0 = kk * 32 + q * 8;
    short8 a0 = ld8(wbp + c * DD + k0);
    short8 a1 = ld8(wbp + (16 + c) * DD + k0);
    short8 u0 = ld8(ubp + c * DD + k0);
    short8 u1 = ld8(ubp + (16 + c) * DD + k0);
    short8 u2 = ld8(ubp + r2 * DD + k0);
    acc[0][0] = __builtin_amdgcn_mfma_f32_16x16x32_bf16(a0, u0, acc[0][0], 0, 0, 0);
    acc[0][1] = __builtin_amdgcn_mfma_f32_16x16x32_bf16(a0, u1, acc[0][1], 0, 0, 0);
    acc[0][2] = __builtin_amdgcn_mfma_f32_16x16x32_bf16(a0, u2, acc[0][2], 0, 0, 0);
    acc[1][0] = __builtin_amdgcn_mfma_f32_16x16x32_bf16(a1, u0, acc[1][0], 0, 0, 0);
    acc[1][1] = __builtin_amdgcn_mfma_f32_16x16x32_bf16(a1, u1, acc[1][1], 0, 0, 0);
    acc[1][2] = __builtin_amdgcn_mfma_f32_16x16x32_bf16(a1, u2, acc[1][2], 0, 0, 0);
  }

  // ------------- softmax over o (row t lives in one quad's 16 lanes) -----
  const float scale = 0.04419417382415922f;  // 1/sqrt(512)
  float attv[2][3][4];
  const bool v2 = (c < 4);  // col 32+c valid iff < 36
#pragma unroll
  for (int mt = 0; mt < 2; ++mt) {
#pragma unroll
    for (int reg = 0; reg < 4; ++reg) {
      float s0 = acc[mt][0][reg] * scale;
      float s1 = acc[mt][1][reg] * scale;
      float s2 = acc[mt][2][reg] * scale;
      float m = fmaxf(s0, s1);
      if (v2) m = fmaxf(m, s2);
#pragma unroll
      for (int off = 1; off < 16; off <<= 1) m = fmaxf(m, __shfl_xor(m, off));
      float e0 = __expf(s0 - m);
      float e1 = __expf(s1 - m);
      float e2 = v2 ? __expf(s2 - m) : 0.f;
      float sum = e0 + e1 + e2;
#pragma unroll
      for (int off = 1; off < 16; off <<= 1) sum += __shfl_xor(sum, off);
      float inv = 1.f / sum;
      attv[mt][0][reg] = e0 * inv;
      attv[mt][1][reg] = e1 * inv;
      attv[mt][2][reg] = e2 * inv;
    }
  }

  // write att (fp32, global) + att_s (bf16, LDS; cols>=36 stay zero)
  float* attb = att_out + (size_t)(wb * BB + b) * TW * TO;
#pragma unroll
  for (int mt = 0; mt < 2; ++mt)
#pragma unroll
    for (int reg = 0; reg < 4; ++reg) {
      int t = mt * 16 + q * 4 + reg;
#pragma unroll
      for (int nt = 0; nt < 3; ++nt) {
        int oo = nt * 16 + c;
        if (oo < TO) {
          attb[t * TO + oo] = attv[mt][nt][reg];
          att_s[wv][t][oo] = f2bf(attv[mt][nt][reg]);
        }
      }
    }
  __syncthreads();

  // ------------- GEMM2: att_V_o[t][d] = sum_o att[t][o]*o[o][d] ---------
  // Swapped operands: D[d][t] layout -> lane (c,q) holds t = mt*16+c and
  // d = d0 + q*4 + reg (4 consecutive d per lane).
  short8 a2[2][2];  // att frags from LDS (reused across all d-tiles)
#pragma unroll
  for (int mt = 0; mt < 2; ++mt)
#pragma unroll
    for (int kk = 0; kk < 2; ++kk)
      a2[mt][kk] = ld8(&att_s[wv][mt * 16 + c][kk * 32 + q * 8]);

  const unsigned short* otp = ot + (size_t)b * DD * 64;
  const float* wrow = w_g + (size_t)wb * TW * DD;
  float* avb = attV_out + (size_t)(wb * BB + b) * TW * DD;  // base == 1 mod 4 floats!
  float lp[2] = {0.f, 0.f};
  float prevA3[2];

  // ---- tile 0 (peeled: head elements d=0..2 stored scalar from q==0) ----
  {
    short8 b0 = ld8(otp + c * 64 + q * 8);
    short8 b1 = ld8(otp + c * 64 + 32 + q * 8);
#pragma unroll
    for (int mt = 0; mt < 2; ++mt) {
      floatx4 a = (floatx4){0.f, 0.f, 0.f, 0.f};
      a = __builtin_amdgcn_mfma_f32_16x16x32_bf16(b0, a2[mt][0], a, 0, 0, 0);
      a = __builtin_amdgcn_mfma_f32_16x16x32_bf16(b1, a2[mt][1], a, 0, 0, 0);
      const int t = mt * 16 + c;
      const int dd = q * 4;
      float4 w4 = *(const float4*)&wrow[t * DD + dd];
      lp[mt] += a[0] * w4.x + a[1] * w4.y + a[2] * w4.z + a[3] * w4.w;
      float up = __shfl_up(a[3], 16);
      if (q == 0) {
        avb[t * DD + 0] = a[0];
        avb[t * DD + 1] = a[1];
        avb[t * DD + 2] = a[2];
      } else {
        float4 st = {up, a[0], a[1], a[2]};
        *(float4*)&avb[t * DD + dd - 1] = st;  // dd-1 == 3 mod 4 -> aligned
      }
      prevA3[mt] = a[3];
    }
  }

  // ---- tiles 1..31: shifted-window aligned float4 stores ----------------
#pragma unroll 4
  for (int nt2 = 1; nt2 < 32; ++nt2) {
    const int d0 = nt2 * 16;
    short8 b0 = ld8(otp + (d0 + c) * 64 + q * 8);
    short8 b1 = ld8(otp + (d0 + c) * 64 + 32 + q * 8);
#pragma unroll
    for (int mt = 0; mt < 2; ++mt) {
      floatx4 a = (floatx4){0.f, 0.f, 0.f, 0.f};
      a = __builtin_amdgcn_mfma_f32_16x16x32_bf16(b0, a2[mt][0], a, 0, 0, 0);
      a = __builtin_amdgcn_mfma_f32_16x16x32_bf16(b1, a2[mt][1], a, 0, 0, 0);
      const int t = mt * 16 + c;
      const int dd = d0 + q * 4;
      float4 w4 = *(const float4*)&wrow[t * DD + dd];
      lp[mt] += a[0] * w4.x + a[1] * w4.y + a[2] * w4.z + a[3] * w4.w;
      float up = __shfl_up(a[3], 16);                 // q>0: a3 of lane q-1
      float carry = __shfl(prevA3[mt], c | 48);       // q==0: a3 of prev tile q=3
      float first = (q == 0) ? carry : up;
      float4 st = {first, a[0], a[1], a[2]};
      *(float4*)&avb[t * DD + dd - 1] = st;           // aligned (base+dd-1 == 0 mod 4)
      prevA3[mt] = a[3];
    }
  }

  // ---- tail element d=511 per row + logits reduction --------------------
#pragma unroll
  for (int mt = 0; mt < 2; ++mt) {
    if (q == 3) avb[(mt * 16 + c) * DD + 511] = prevA3[mt];
    float s = lp[mt];
    s += __shfl_xor(s, 16);
    s += __shfl_xor(s, 32);
    if (lane < 16)
      logits_ws[(size_t)(wb * BB + b) * TW + mt * 16 + lane] = s;
  }
}

// ---- loss: log_softmax over Bo + masked mean -----------------------------
__global__ __launch_bounds__(64) void loss_kernel(
    const float* __restrict__ logits, const int* __restrict__ mask,
    float* __restrict__ out) {
  int wb = blockIdx.x, lane = threadIdx.x;  // lane = b
  const float* lrow = logits + ((size_t)wb * BB + lane) * TW;
  float accv = 0.f, nnm = 0.f;
  for (int t = 0; t < TW; ++t) {
    float v = lrow[t];
    float m = v;
#pragma unroll
    for (int off = 1; off < 64; off <<= 1) m = fmaxf(m, __shfl_xor(m, off));
    float e = __expf(v - m);
    float s = e;
#pragma unroll
    for (int off = 1; off < 64; off <<= 1) s += __shfl_xor(s, off);
    float diag = __shfl(v, wb);  // logits[wb][wb][t]
    float lsm = diag - m - __logf(s);
    float keep = 1.f - (float)mask[wb * TW + t];
    accv += lsm * keep;
    nnm += keep;
  }
  if (lane == 0) atomicAdd(out, -(accv / (nnm + 1e-6f)) * (1.f / 64.f));
}

// ---- launch --------------------------------------------------------------
extern "C" void kernel_launch(void* const* d_in, const int* in_sizes, int n_in,
                              void* d_out, int out_size, void* d_ws, size_t ws_size,
                              hipStream_t stream) {
  const float* o_g = (const float*)d_in[0];   // (64,36,512) f32
  const float* u_g = (const float*)d_in[1];   // (64,36,512) f32
  const float* w_g = (const float*)d_in[2];   // (64,32,512) f32
  const int* mask  = (const int*)d_in[3];     // (64,32) i32

  float* out = (float*)d_out;
  float* att_out  = out + 1;                       // 64*64*32*36 = 4,718,592
  float* attV_out = out + 1 + (size_t)BB * BB * TW * TO;  // 64*64*32*512

  char* ws = (char*)d_ws;
  unsigned short* wbf = (unsigned short*)(ws + 0);         // 2,097,152 B
  unsigned short* ubf = (unsigned short*)(ws + 2097152);   // 2,359,296 B
  unsigned short* ot  = (unsigned short*)(ws + 4456448);   // 4,194,304 B
  float* logits       = (float*)(ws + 8650752);            //   524,288 B

  hipMemsetAsync(d_out, 0, sizeof(float), stream);  // loss accumulator
  prep_kernel<<<1216, 256, 0, stream>>>(o_g, u_g, w_g, wbf, ubf, ot);
  main_kernel<<<dim3(BB, BB / 4), 256, 0, stream>>>(w_g, wbf, ubf, ot, logits,
                                                    att_out, attV_out);
  loss_kernel<<<BB, 64, 0, stream>>>(logits, mask, out);
}

// Round 2
// 413.220 us; speedup vs baseline: 1.1373x; 1.0534x over previous
//
#include <hip/hip_runtime.h>

#define BB 64
#define TO 36
#define TW 32
#define DD 512

typedef short short8 __attribute__((ext_vector_type(8)));
typedef float floatx4 __attribute__((ext_vector_type(4)));

// ---- helpers -------------------------------------------------------------

__device__ __forceinline__ unsigned short f2bf(float f) {
  // round-to-nearest-even fp32 -> bf16 (inputs are sane, no NaN handling)
  unsigned int x = __builtin_bit_cast(unsigned int, f);
  x += 0x7FFFu + ((x >> 16) & 1u);
  return (unsigned short)(x >> 16);
}

__device__ __forceinline__ short8 ld8(const unsigned short* p) {
  return __builtin_bit_cast(short8, *(const uint4*)p);
}

// ---- prep: f32->bf16 conversions + o transpose ---------------------------
// blocks 0..511    : w  (64*32*512 = 1,048,576 floats, 8/thread)
// blocks 512..1087 : u  (64*36*512 = 1,179,648 floats, 8/thread)
// blocks 1088..1215: ot[b][d][64] bf16, o-index padded 36->64 with zeros
__global__ __launch_bounds__(256) void prep_kernel(
    const float* __restrict__ o_g, const float* __restrict__ u_g,
    const float* __restrict__ w_g, unsigned short* __restrict__ wbf,
    unsigned short* __restrict__ ubf, unsigned short* __restrict__ ot) {
  const int blk = blockIdx.x, tid = threadIdx.x;
  if (blk < 512) {
    int i8 = blk * 256 + tid;
    const float4* src = (const float4*)w_g;
    float4 f0 = src[i8 * 2], f1 = src[i8 * 2 + 1];
    uint4 d;
    d.x = (unsigned)f2bf(f0.x) | ((unsigned)f2bf(f0.y) << 16);
    d.y = (unsigned)f2bf(f0.z) | ((unsigned)f2bf(f0.w) << 16);
    d.z = (unsigned)f2bf(f1.x) | ((unsigned)f2bf(f1.y) << 16);
    d.w = (unsigned)f2bf(f1.z) | ((unsigned)f2bf(f1.w) << 16);
    ((uint4*)wbf)[i8] = d;
  } else if (blk < 1088) {
    int i8 = (blk - 512) * 256 + tid;
    const float4* src = (const float4*)u_g;
    float4 f0 = src[i8 * 2], f1 = src[i8 * 2 + 1];
    uint4 d;
    d.x = (unsigned)f2bf(f0.x) | ((unsigned)f2bf(f0.y) << 16);
    d.y = (unsigned)f2bf(f0.z) | ((unsigned)f2bf(f0.w) << 16);
    d.z = (unsigned)f2bf(f1.x) | ((unsigned)f2bf(f1.y) << 16);
    d.w = (unsigned)f2bf(f1.z) | ((unsigned)f2bf(f1.w) << 16);
    ((uint4*)ubf)[i8] = d;
  } else {
    int t2 = (blk - 1088) * 256 + tid;  // 32768 threads: (b, d)
    int b = t2 >> 9, d = t2 & 511;
    uint4 bufv[8];
    unsigned short* buf = (unsigned short*)bufv;
#pragma unroll
    for (int o = 0; o < 64; ++o)
      buf[o] = (o < TO) ? f2bf(o_g[((b * TO + o) << 9) + d]) : (unsigned short)0;
    uint4* dst = (uint4*)(ot + ((size_t)((b << 9) + d) << 6));
#pragma unroll
    for (int i = 0; i < 8; ++i) dst[i] = bufv[i];
  }
}

// ---- main: fused scores->softmax->att_V_o->logits ------------------------
// Block = 4 waves = 2 wb-slices x 2 d-halves (all sharing one b).
// Both waves of a wb-pair redundantly compute GEMM1+softmax (bit-identical),
// so NO mid-kernel barrier is needed: LDS value-bytes are written identically
// by both waves, pad-bytes only by the zero phase. Each wave then runs GEMM2
// over its 16 d-tiles (256-wide half of D). attV/att use nontemporal stores
// to keep ot/w resident in L2. Logits halves combine via one end barrier.
__global__ __launch_bounds__(256) void main_kernel(
    const float* __restrict__ w_g,
    const unsigned short* __restrict__ wbf,
    const unsigned short* __restrict__ ubf,
    const unsigned short* __restrict__ ot,
    float* __restrict__ logits_ws,
    float* __restrict__ att_out,
    float* __restrict__ attV_out) {
  const int b = blockIdx.x;
  const int wv = threadIdx.x >> 6;          // wave 0..3
  const int sl = wv >> 1;                   // wb slice 0..1
  const int dhalf = wv & 1;                 // d-half 0..1
  const int wb = blockIdx.y * 2 + sl;
  const int lane = threadIdx.x & 63;
  const int c = lane & 15;   // col within 16x16 tile
  const int q = lane >> 4;   // quad 0..3

  __shared__ unsigned short att_s[2][TW][72];  // per-slice bf16 att, K-pad to 64
  __shared__ float lsum[4][2][16];             // logits half-sums

  // zero ONLY the pad region (cols 36..71 of each row): 32 rows * 18 dwords
  {
    unsigned int* base = (unsigned int*)&att_s[sl][0][0];
#pragma unroll
    for (int i = 0; i < 9; ++i) {
      int idx = i * 64 + lane;              // 0..575
      int row = idx / 18, cd = idx - row * 18;
      base[row * 36 + 18 + cd] = 0u;
    }
  }

  // ---------------- GEMM1: scores[t][o] = w[t,:].u[o,:] ------------------
  const unsigned short* wbp = wbf + (size_t)wb * TW * DD;
  const unsigned short* ubp = ubf + (size_t)b * TO * DD;

  floatx4 acc[2][3];
#pragma unroll
  for (int i = 0; i < 2; ++i)
#pragma unroll
    for (int j = 0; j < 3; ++j) acc[i][j] = (floatx4){0.f, 0.f, 0.f, 0.f};

  int r2 = 32 + c; if (r2 > 35) r2 = 35;  // clamp: cols 36..47 discarded later
#pragma unroll 2
  for (int kk = 0; kk < 16; ++kk) {
    int k0 = kk * 32 + q * 8;
    short8 a0 = ld8(wbp + c * DD + k0);
    short8 a1 = ld8(wbp + (16 + c) * DD + k0);
    short8 u0 = ld8(ubp + c * DD + k0);
    short8 u1 = ld8(ubp + (16 + c) * DD + k0);
    short8 u2 = ld8(ubp + r2 * DD + k0);
    acc[0][0] = __builtin_amdgcn_mfma_f32_16x16x32_bf16(a0, u0, acc[0][0], 0, 0, 0);
    acc[0][1] = __builtin_amdgcn_mfma_f32_16x16x32_bf16(a0, u1, acc[0][1], 0, 0, 0);
    acc[0][2] = __builtin_amdgcn_mfma_f32_16x16x32_bf16(a0, u2, acc[0][2], 0, 0, 0);
    acc[1][0] = __builtin_amdgcn_mfma_f32_16x16x32_bf16(a1, u0, acc[1][0], 0, 0, 0);
    acc[1][1] = __builtin_amdgcn_mfma_f32_16x16x32_bf16(a1, u1, acc[1][1], 0, 0, 0);
    acc[1][2] = __builtin_amdgcn_mfma_f32_16x16x32_bf16(a1, u2, acc[1][2], 0, 0, 0);
  }

  // ------------- softmax over o (row t lives in one quad's 16 lanes) -----
  const float scale = 0.04419417382415922f;  // 1/sqrt(512)
  float attv[2][3][4];
  const bool v2 = (c < 4);  // col 32+c valid iff < 36
#pragma unroll
  for (int mt = 0; mt < 2; ++mt) {
#pragma unroll
    for (int reg = 0; reg < 4; ++reg) {
      float s0 = acc[mt][0][reg] * scale;
      float s1 = acc[mt][1][reg] * scale;
      float s2 = acc[mt][2][reg] * scale;
      float m = fmaxf(s0, s1);
      if (v2) m = fmaxf(m, s2);
#pragma unroll
      for (int off = 1; off < 16; off <<= 1) m = fmaxf(m, __shfl_xor(m, off));
      float e0 = __expf(s0 - m);
      float e1 = __expf(s1 - m);
      float e2 = v2 ? __expf(s2 - m) : 0.f;
      float sum = e0 + e1 + e2;
#pragma unroll
      for (int off = 1; off < 16; off <<= 1) sum += __shfl_xor(sum, off);
      float inv = 1.f / sum;
      attv[mt][0][reg] = e0 * inv;
      attv[mt][1][reg] = e1 * inv;
      attv[mt][2][reg] = e2 * inv;
    }
  }

  // write att (fp32 global, nontemporal, only dhalf==0) + att_s (bf16 LDS,
  // both waves write bit-identical values -> benign race, no barrier)
  float* attb = att_out + (size_t)(wb * BB + b) * TW * TO;
#pragma unroll
  for (int mt = 0; mt < 2; ++mt)
#pragma unroll
    for (int reg = 0; reg < 4; ++reg) {
      int t = mt * 16 + q * 4 + reg;
#pragma unroll
      for (int nt = 0; nt < 3; ++nt) {
        int oo = nt * 16 + c;
        if (oo < TO) {
          if (dhalf == 0)
            __builtin_nontemporal_store(attv[mt][nt][reg], &attb[t * TO + oo]);
          att_s[sl][t][oo] = f2bf(attv[mt][nt][reg]);
        }
      }
    }

  // ------------- GEMM2: att_V_o[t][d] = sum_o att[t][o]*o[o][d] ---------
  // Swapped operands: lane (c,q) holds t = mt*16+c, d = d0 + q*4 + reg.
  short8 a2[2][2];  // att frags from LDS (own wave's writes -> lgkmcnt only)
#pragma unroll
  for (int mt = 0; mt < 2; ++mt)
#pragma unroll
    for (int kk = 0; kk < 2; ++kk)
      a2[mt][kk] = ld8(&att_s[sl][mt * 16 + c][kk * 32 + q * 8]);

  const unsigned short* otp = ot + (size_t)b * DD * 64;
  const float* wrow = w_g + (size_t)wb * TW * DD;
  float* avb = attV_out + (size_t)(wb * BB + b) * TW * DD;  // base == 1 mod 4!
  float lp[2] = {0.f, 0.f};
  float prevA3[2];
  int tstart, tend;

  if (dhalf == 0) {
    // ---- tile 0 (peeled: head elements d=0..2 stored scalar from q==0) --
    short8 b0 = ld8(otp + c * 64 + q * 8);
    short8 b1 = ld8(otp + c * 64 + 32 + q * 8);
#pragma unroll
    for (int mt = 0; mt < 2; ++mt) {
      floatx4 a = (floatx4){0.f, 0.f, 0.f, 0.f};
      a = __builtin_amdgcn_mfma_f32_16x16x32_bf16(b0, a2[mt][0], a, 0, 0, 0);
      a = __builtin_amdgcn_mfma_f32_16x16x32_bf16(b1, a2[mt][1], a, 0, 0, 0);
      const int t = mt * 16 + c;
      const int dd = q * 4;
      float4 w4 = *(const float4*)&wrow[t * DD + dd];
      lp[mt] += a[0] * w4.x + a[1] * w4.y + a[2] * w4.z + a[3] * w4.w;
      float up = __shfl_up(a[3], 16);
      if (q == 0) {
        __builtin_nontemporal_store(a[0], &avb[t * DD + 0]);
        __builtin_nontemporal_store(a[1], &avb[t * DD + 1]);
        __builtin_nontemporal_store(a[2], &avb[t * DD + 2]);
      } else {
        floatx4 st = {up, a[0], a[1], a[2]};
        __builtin_nontemporal_store(st, (floatx4*)&avb[t * DD + dd - 1]);
      }
      prevA3[mt] = a[3];
    }
    tstart = 1; tend = 16;
  } else {
    // ---- pre-peel tile 15 (MFMA only) to obtain the d=255 carry ---------
    short8 b0 = ld8(otp + (240 + c) * 64 + q * 8);
    short8 b1 = ld8(otp + (240 + c) * 64 + 32 + q * 8);
#pragma unroll
    for (int mt = 0; mt < 2; ++mt) {
      floatx4 a = (floatx4){0.f, 0.f, 0.f, 0.f};
      a = __builtin_amdgcn_mfma_f32_16x16x32_bf16(b0, a2[mt][0], a, 0, 0, 0);
      a = __builtin_amdgcn_mfma_f32_16x16x32_bf16(b1, a2[mt][1], a, 0, 0, 0);
      prevA3[mt] = a[3];
    }
    tstart = 16; tend = 32;
  }

  // ---- main tiles: shifted-window aligned nontemporal float4 stores -----
#pragma unroll 4
  for (int nt2 = tstart; nt2 < tend; ++nt2) {
    const int d0 = nt2 * 16;
    short8 b0 = ld8(otp + (d0 + c) * 64 + q * 8);
    short8 b1 = ld8(otp + (d0 + c) * 64 + 32 + q * 8);
#pragma unroll
    for (int mt = 0; mt < 2; ++mt) {
      floatx4 a = (floatx4){0.f, 0.f, 0.f, 0.f};
      a = __builtin_amdgcn_mfma_f32_16x16x32_bf16(b0, a2[mt][0], a, 0, 0, 0);
      a = __builtin_amdgcn_mfma_f32_16x16x32_bf16(b1, a2[mt][1], a, 0, 0, 0);
      const int t = mt * 16 + c;
      const int dd = d0 + q * 4;
      float4 w4 = *(const float4*)&wrow[t * DD + dd];
      lp[mt] += a[0] * w4.x + a[1] * w4.y + a[2] * w4.z + a[3] * w4.w;
      float up = __shfl_up(a[3], 16);                 // q>0: a3 of lane q-1
      float carry = __shfl(prevA3[mt], c | 48);       // q==0: a3 of prev tile q=3
      float first = (q == 0) ? carry : up;
      floatx4 st = {first, a[0], a[1], a[2]};
      __builtin_nontemporal_store(st, (floatx4*)&avb[t * DD + dd - 1]);
      prevA3[mt] = a[3];
    }
  }

  // ---- tail element d=511 + logits: combine the two d-halves ------------
#pragma unroll
  for (int mt = 0; mt < 2; ++mt) {
    if (dhalf == 1 && q == 3)
      __builtin_nontemporal_store(prevA3[mt], &avb[(mt * 16 + c) * DD + 511]);
    float s = lp[mt];
    s += __shfl_xor(s, 16);
    s += __shfl_xor(s, 32);
    if (lane < 16) lsum[wv][mt][lane] = s;
  }
  __syncthreads();
  if (dhalf == 0 && lane < 16) {
#pragma unroll
    for (int mt = 0; mt < 2; ++mt) {
      float tot = lsum[wv][mt][lane] + lsum[wv + 1][mt][lane];
      logits_ws[(size_t)(wb * BB + b) * TW + mt * 16 + lane] = tot;
    }
  }
}

// ---- loss: log_softmax over Bo + masked mean -----------------------------
__global__ __launch_bounds__(64) void loss_kernel(
    const float* __restrict__ logits, const int* __restrict__ mask,
    float* __restrict__ out) {
  int wb = blockIdx.x, lane = threadIdx.x;  // lane = b
  const float* lrow = logits + ((size_t)wb * BB + lane) * TW;
  float accv = 0.f, nnm = 0.f;
  for (int t = 0; t < TW; ++t) {
    float v = lrow[t];
    float m = v;
#pragma unroll
    for (int off = 1; off < 64; off <<= 1) m = fmaxf(m, __shfl_xor(m, off));
    float e = __expf(v - m);
    float s = e;
#pragma unroll
    for (int off = 1; off < 64; off <<= 1) s += __shfl_xor(s, off);
    float diag = __shfl(v, wb);  // logits[wb][wb][t]
    float lsm = diag - m - __logf(s);
    float keep = 1.f - (float)mask[wb * TW + t];
    accv += lsm * keep;
    nnm += keep;
  }
  if (lane == 0) atomicAdd(out, -(accv / (nnm + 1e-6f)) * (1.f / 64.f));
}

// ---- launch --------------------------------------------------------------
extern "C" void kernel_launch(void* const* d_in, const int* in_sizes, int n_in,
                              void* d_out, int out_size, void* d_ws, size_t ws_size,
                              hipStream_t stream) {
  const float* o_g = (const float*)d_in[0];   // (64,36,512) f32
  const float* u_g = (const float*)d_in[1];   // (64,36,512) f32
  const float* w_g = (const float*)d_in[2];   // (64,32,512) f32
  const int* mask  = (const int*)d_in[3];     // (64,32) i32

  float* out = (float*)d_out;
  float* att_out  = out + 1;                       // 64*64*32*36 = 4,718,592
  float* attV_out = out + 1 + (size_t)BB * BB * TW * TO;  // 64*64*32*512

  char* ws = (char*)d_ws;
  unsigned short* wbf = (unsigned short*)(ws + 0);         // 2,097,152 B
  unsigned short* ubf = (unsigned short*)(ws + 2097152);   // 2,359,296 B
  unsigned short* ot  = (unsigned short*)(ws + 4456448);   // 4,194,304 B
  float* logits       = (float*)(ws + 8650752);            //   524,288 B

  hipMemsetAsync(d_out, 0, sizeof(float), stream);  // loss accumulator
  prep_kernel<<<1216, 256, 0, stream>>>(o_g, u_g, w_g, wbf, ubf, ot);
  main_kernel<<<dim3(BB, BB / 2), 256, 0, stream>>>(w_g, wbf, ubf, ot, logits,
                                                    att_out, attV_out);
  loss_kernel<<<BB, 64, 0, stream>>>(logits, mask, out);
}